// Round 7
// baseline (318.706 us; speedup 1.0000x reference)
//
#include <hip/hip_runtime.h>

typedef unsigned int   u32;
typedef unsigned short u16;

typedef _Float16 h2  __attribute__((ext_vector_type(2)));
typedef _Float16 h8  __attribute__((ext_vector_type(8)));
typedef float    f32x4 __attribute__((ext_vector_type(4)));

#define M_TOK 128

__device__ __forceinline__ u16 f2h_(float f) {
    _Float16 h = (_Float16)f; return __builtin_bit_cast(u16, h);
}
__device__ __forceinline__ float h2f_(u16 b) {
    _Float16 h = __builtin_bit_cast(_Float16, b); return (float)h;
}
__device__ __forceinline__ void acc8(uint4 v, float* s) {
#pragma unroll
    for (int i = 0; i < 4; ++i) {
        u32 w = ((const u32*)&v)[i];
        s[2 * i]     += h2f_((u16)(w & 0xFFFF));
        s[2 * i + 1] += h2f_((u16)(w >> 16));
    }
}

// AWQ nibble order: n&7 = j sits at bit position SH[j]
__constant__ int SHC[8] = {0, 16, 4, 20, 8, 24, 12, 28};

// ---------------------------------------------------------------------------
// pack_zs: (qz, sc) -> zs[g][n] u32 { lo16: fp16(-(1024+z)), hi16: fp16(sc) }
// ---------------------------------------------------------------------------
__launch_bounds__(256)
__global__ void pack_zs(const int* __restrict__ qz, const float* __restrict__ sc,
                        u32* __restrict__ zs, int qws, int scs, int Ncols, int total) {
    const int idx = blockIdx.x * 256 + threadIdx.x;
    if (idx >= total) return;
    const int g = idx / Ncols, n = idx - g * Ncols;
    const u32 d = (u32)qz[(size_t)g * qws + (n >> 3)];
    const u32 zj = (d >> SHC[n & 7]) & 15u;
    const u32 mz = 0xE400u | zj;                    // fp16 -(1024+z)
    const u16 sh = f2h_(sc[(size_t)g * scs + n]);
    zs[(size_t)g * Ncols + n] = mz | ((u32)sh << 16);
}

// A-fragment-major layout: elem offset for logical (m, k):
//   kb=k/32, q=(k/8)&3, j=k&7, mt=m/16, l16=m&15
//   off = ((kb*8+mt)*64 + q*16 + l16)*8 + j    (fp16 elements)

// ---------------------------------------------------------------------------
// RMSNorm: one block per token row, fp32 in -> fp16 out in Afrag layout
// ---------------------------------------------------------------------------
__launch_bounds__(256)
__global__ void rmsnorm_k(const float* __restrict__ in, const float* __restrict__ w,
                          u16* __restrict__ out) {
    const int row = blockIdx.x;
    const float* x = in + (size_t)row * 4096;
    float ss = 0.f;
#pragma unroll
    for (int j = 0; j < 16; ++j) {
        float v = x[threadIdx.x + 256 * j];
        ss += v * v;
    }
#pragma unroll
    for (int off = 32; off > 0; off >>= 1) ss += __shfl_down(ss, off, 64);
    __shared__ float ws4[4];
    if ((threadIdx.x & 63) == 0) ws4[threadIdx.x >> 6] = ss;
    __syncthreads();
    float total = ws4[0] + ws4[1] + ws4[2] + ws4[3];
    float r = rsqrtf(total * (1.f / 4096.f) + 1e-6f);
    const int mt = row >> 4, l16 = row & 15;
#pragma unroll
    for (int c2 = 0; c2 < 2; ++c2) {
        int c = threadIdx.x * 2 + c2;
        int kb = c >> 2, qq = c & 3;
        u16 o8[8];
#pragma unroll
        for (int j = 0; j < 8; ++j) {
            int i = c * 8 + j;
            o8[j] = f2h_(x[i] * r * w[i]);
        }
        *(uint4*)(out + ((size_t)(kb * 8 + mt) * 64 + qq * 16 + l16) * 8) = *(const uint4*)o8;
    }
}

// ---------------------------------------------------------------------------
// AWQ GEMM, barrier-free, vmcnt-hazard-free schedule.
// MSPLIT=1: wave = 128m x 32n, block = 4 distinct 32n strips (gu).
// MSPLIT=2: wave = 64m x 32n, block = 2 n-strips x 2 m-halves; the mh pair
//   duplicates dequant privately (weights are L2-resident per XCD for
//   qkv/o/dn, so duplicate reads are cache hits) -> 2x waves for TLP.
// Per-step order (the fix): (1) bv ds_reads FIRST in the LDS queue,
// (2) bpermutes for tile i+1 issued before MFMA (latency hides under MFMA),
// (3) setprio'd MFMA cluster with L1/L2-hot afc loads and NO earlier-issued
// HBM load in the vmcnt queue, (4) ldraw(i+3) AFTER the MFMAs (3-deep raw
// ring rv_n/rv_nn -> ~2 steps of slack per HBM load), (5) emit+ds_writes.
// vmcnt drains in issue order, so placing ldraw before the afc loads (rounds
// 4-6) made every step wait a full HBM latency -- that was the ~14% MfmaUtil
// ceiling.
// ---------------------------------------------------------------------------
template<int MSPLIT>
__launch_bounds__(256, MSPLIT == 2 ? 4 : 3)
__global__ void gemm_awq(const u16* __restrict__ A, const u32* __restrict__ zs,
                         const int* __restrict__ qw, u16* __restrict__ part,
                         int qws, int N, int K, int kchunk) {
    constexpr int MT = (MSPLIT == 2) ? 4 : 8;
    __shared__ __align__(16) char ldsB[4 * 9216];   // per-wave 2 bufs x 32n x 64k

    const int tid = threadIdx.x, w = tid >> 6, lane = tid & 63;
    const int q = lane >> 4, l16 = lane & 15;
    const int mh = (MSPLIT == 2) ? (w >> 1) : 0;
    // bijective XCD-chunk swizzle (m204 form)
    const int nwg = gridDim.x, bid = blockIdx.x;
    const int qq8 = nwg >> 3, r8 = nwg & 7, xcd = bid & 7, boff = bid >> 3;
    const int bx = (xcd < r8 ? xcd * (qq8 + 1) : r8 * (qq8 + 1) + (xcd - r8) * qq8) + boff;
    const int n0w = (MSPLIT == 2) ? (bx * 64 + (w & 1) * 32) : (bx * 128 + w * 32);
    const int pc0 = n0w >> 3;
    const int kp = lane & 31, h = lane >> 5;
    const int sk = blockIdx.y, kc0 = sk * kchunk, kend = min(kc0 + kchunk, K);

    char* buf0 = ldsB + w * 9216;                    // private to this wave
    char* buf1 = buf0 + 4608;
    const u16* Ala = A + lane * 8;
    const int* qws_base = qw + pc0;
    const u32* zsA = zs + n0w + h * 8;
    const u32* zsB = zs + n0w + 16 + h * 8;

    f32x4 acc[MT][2] = {};
    uint4 za0, za1, zb0, zb1;       // current group's packed (mz, sc)

    auto ldraw = [&](int k0) -> uint4 {
        return *(const uint4*)(qws_base + (size_t)(k0 + lane) * qws);
    };
    auto loadzs = [&](int g) {
        za0 = *(const uint4*)(zsA + (size_t)g * N);
        za1 = *(const uint4*)(zsA + (size_t)g * N + 4);
        zb0 = *(const uint4*)(zsB + (size_t)g * N);
        zb1 = *(const uint4*)(zsB + (size_t)g * N + 4);
    };
    // phase 1 of dequant: issue the 8 bpermutes (results consumed later)
    auto bperm8 = [&](uint4 rv, int* b) {
        const int i0 = kp * 8, i1 = i0 + 4;
        b[0] = __builtin_amdgcn_ds_bpermute(i0, (int)rv.x);
        b[1] = __builtin_amdgcn_ds_bpermute(i0, (int)rv.y);
        b[2] = __builtin_amdgcn_ds_bpermute(i0, (int)rv.z);
        b[3] = __builtin_amdgcn_ds_bpermute(i0, (int)rv.w);
        b[4] = __builtin_amdgcn_ds_bpermute(i1, (int)rv.x);
        b[5] = __builtin_amdgcn_ds_bpermute(i1, (int)rv.y);
        b[6] = __builtin_amdgcn_ds_bpermute(i1, (int)rv.z);
        b[7] = __builtin_amdgcn_ds_bpermute(i1, (int)rv.w);
    };
    // phase 2: select + dequant full 32n x 64k tile into buf
    auto emit_all = [&](const int* b, char* buf) {
        u32 qd0 = (u32)(h ? b[1] : b[0]);
        u32 qd1 = (u32)(h ? b[5] : b[4]);
        u32 qd2 = (u32)(h ? b[3] : b[2]);
        u32 qd3 = (u32)(h ? b[7] : b[6]);
        auto emit8 = [&](u32 w0, u32 w1, int nb, uint4 z0, uint4 z1) {
            char* bb = buf + kp * 4 + nb * 144;
            u32 w0s = w0 >> 4, w1s = w1 >> 4;
            auto em = [&](int j, u32 a0, u32 a1, int bsel, u32 zsj) {
                h2 mz = __builtin_bit_cast(h2, __builtin_amdgcn_perm(zsj, zsj, 0x01000100u));
                h2 s2 = __builtin_bit_cast(h2, __builtin_amdgcn_perm(zsj, zsj, 0x03020302u));
                u32 t = __builtin_amdgcn_perm(a1, a0, (u32)(bsel | ((bsel + 4) << 16)));
                u32 u = (t & 0x000F000Fu) | 0x64006400u;
                h2 v = (__builtin_bit_cast(h2, u) + mz) * s2;
                *(u32*)(bb + j * 144) = __builtin_bit_cast(u32, v);
            };
            em(0, w0, w1, 0, z0.x);  em(4, w0, w1, 1, z1.x);
            em(1, w0, w1, 2, z0.y);  em(5, w0, w1, 3, z1.y);
            em(2, w0s, w1s, 0, z0.z); em(6, w0s, w1s, 1, z1.z);
            em(3, w0s, w1s, 2, z0.w); em(7, w0s, w1s, 3, z1.w);
        };
        emit8(qd0, qd1, h * 8, za0, za1);
        emit8(qd2, qd3, 16 + h * 8, zb0, zb1);
    };

    // ---- prologue: dequant tile 0; raw ring depth 3 ----
    loadzs(kc0 >> 7);
    uint4 rv0 = ldraw(kc0);
    uint4 rv_n = {0, 0, 0, 0}, rv_nn = {0, 0, 0, 0};
    if (kc0 + 64 < kend)  rv_n  = ldraw(kc0 + 64);
    if (kc0 + 128 < kend) rv_nn = ldraw(kc0 + 128);
    {
        int bp0[8];
        bperm8(rv0, bp0);
        emit_all(bp0, buf0);
    }
    if (((kc0 + 64) & 127) == 0 && kc0 + 64 < kend)
        loadzs((kc0 + 64) >> 7);        // mid-group chunk start (dn)

    // ---- main loop: barrier-free, same-wave in-order LDS pipeline ----
    char* cur = buf0; char* nxt = buf1;
    int bp[8];
    for (int k0 = kc0; k0 < kend; k0 += 64) {
        const bool kn1 = (k0 + 64) < kend, kn3 = (k0 + 192) < kend;
        // (1) B-fragment reads: FIRST DS ops of the step
        uint4 bv[2][2];
#pragma unroll
        for (int c = 0; c < 2; ++c)
#pragma unroll
            for (int nt = 0; nt < 2; ++nt)
                bv[c][nt] = *(const uint4*)(cur + (nt * 16 + l16) * 144 + c * 64 + q * 16);
        // (2) bpermutes for tile i+1: latency hides under the MFMA cluster
        if (kn1) bperm8(rv_n, bp);
        // (3) MFMA(i): afc loads are L1/L2-hot and nothing older is in vmcnt
        const int kb = k0 >> 5;
        __builtin_amdgcn_s_setprio(1);
#pragma unroll
        for (int c = 0; c < 2; ++c) {
            uint4 afc[MT];
#pragma unroll
            for (int mt = 0; mt < MT; ++mt)
                afc[mt] = *(const uint4*)(Ala + (size_t)((kb + c) * 8 + mh * MT + mt) * 512);
#pragma unroll
            for (int mt = 0; mt < MT; ++mt)
#pragma unroll
                for (int nt = 0; nt < 2; ++nt)
                    acc[mt][nt] = __builtin_amdgcn_mfma_f32_16x16x32_f16(
                        __builtin_bit_cast(h8, afc[mt]),
                        __builtin_bit_cast(h8, bv[c][nt]),
                        acc[mt][nt], 0, 0, 0);
        }
        __builtin_amdgcn_s_setprio(0);
        // (4) HBM raw prefetch AFTER the MFMAs -> never ahead of afc in vmcnt
        uint4 rv_f = {0, 0, 0, 0};
        if (kn3) rv_f = ldraw(k0 + 192);
        // (5) finish dequant of tile i+1 into nxt
        if (kn1) emit_all(bp, nxt);
        if (((k0 + 128) & 127) == 0 && (k0 + 128) < kend)
            loadzs((k0 + 128) >> 7);    // zs(group+1), used next step
        rv_n = rv_nn; rv_nn = rv_f;
        char* t = cur; cur = nxt; nxt = t;
    }

    // ---- epilogue: fp16 partial store ----
    u16* pp = part + (size_t)sk * M_TOK * N;
#pragma unroll
    for (int mt = 0; mt < MT; ++mt)
#pragma unroll
        for (int nt = 0; nt < 2; ++nt) {
            const int n = n0w + nt * 16 + l16;
#pragma unroll
            for (int r = 0; r < 4; ++r) {
                const int m = (mh * MT + mt) * 16 + q * 4 + r;
                pp[(size_t)m * N + n] = f2h_(acc[mt][nt][r]);
            }
        }
}

// ---------------------------------------------------------------------------
__launch_bounds__(256)
__global__ void reduce_to_afrag(const u16* __restrict__ part, u16* __restrict__ out,
                                int SK) {
    const int idx = blockIdx.x * 256 + threadIdx.x;
    const int m = idx >> 9, c = idx & 511;
    float s[8] = {};
    for (int k = 0; k < SK; ++k)
        acc8(*(const uint4*)(part + (size_t)k * 524288 + (size_t)m * 4096 + c * 8), s);
    const int kb = c >> 2, qq = c & 3, mt = m >> 4, l16 = m & 15;
    u16 o8[8];
#pragma unroll
    for (int j = 0; j < 8; ++j) o8[j] = f2h_(s[j]);
    *(uint4*)(out + ((size_t)(kb * 8 + mt) * 64 + qq * 16 + l16) * 8) = *(const uint4*)o8;
}

__launch_bounds__(256)
__global__ void reduce_add_f32(const u16* __restrict__ part, const float* __restrict__ resin,
                               float* __restrict__ out, int SK) {
    const int idx = blockIdx.x * 256 + threadIdx.x;
    const size_t base = (size_t)idx * 8;
    float s[8];
    *(float4*)&s[0] = *(const float4*)(resin + base);
    *(float4*)&s[4] = *(const float4*)(resin + base + 4);
    for (int k = 0; k < SK; ++k)
        acc8(*(const uint4*)(part + (size_t)k * 524288 + base), s);
    *(float4*)(out + base)     = *(const float4*)&s[0];
    *(float4*)(out + base + 4) = *(const float4*)&s[4];
}

__launch_bounds__(256)
__global__ void silu_mul(const u16* __restrict__ part, u16* __restrict__ act, int SK) {
    const int idx = blockIdx.x * 256 + threadIdx.x;
    const int m = idx / 1376, c = idx - m * 1376;
    const int nb = c * 8;
    float g[8] = {}, u[8] = {};
    for (int k = 0; k < SK; ++k) {
        const size_t base = (size_t)k * 2818048 + (size_t)m * 22016 + nb;
        acc8(*(const uint4*)(part + base), g);
        acc8(*(const uint4*)(part + base + 11008), u);
    }
    const int kb = nb >> 5, qq = (nb >> 3) & 3, mt = m >> 4, l16 = m & 15;
    u16 o8[8];
#pragma unroll
    for (int j = 0; j < 8; ++j) {
        float a = g[j] / (1.f + __expf(-g[j])) * u[j];
        o8[j] = f2h_(a);
    }
    *(uint4*)(act + ((size_t)(kb * 8 + mt) * 64 + qq * 16 + l16) * 8) = *(const uint4*)o8;
}

// ---------------------------------------------------------------------------
extern "C" void kernel_launch(void* const* d_in, const int* in_sizes, int n_in,
                              void* d_out, int out_size, void* d_ws, size_t ws_size,
                              hipStream_t stream) {
    const float* x      = (const float*)d_in[0];
    const float* ln1_w  = (const float*)d_in[1];
    const float* ln2_w  = (const float*)d_in[2];
    const int*   qkv_qw = (const int*)d_in[3];
    const int*   qkv_qz = (const int*)d_in[4];
    const float* qkv_sc = (const float*)d_in[5];
    const int*   o_qw   = (const int*)d_in[6];
    const int*   o_qz   = (const int*)d_in[7];
    const float* o_sc   = (const float*)d_in[8];
    const int*   gu_qw  = (const int*)d_in[9];
    const int*   gu_qz  = (const int*)d_in[10];
    const float* gu_sc  = (const float*)d_in[11];
    const int*   dn_qw  = (const int*)d_in[12];
    const int*   dn_qz  = (const int*)d_in[13];
    const float* dn_sc  = (const float*)d_in[14];
    float* out = (float*)d_out;

    // ws layout (~53.9 MB; >= 70.8 MB available, proven in round 3)
    char* ws = (char*)d_ws;
    u16*   pbuf = (u16*)(ws);                 // partials: max 45.1 MB (gu SK8)
    u32*   zsb  = (u32*)(ws + 45088768);      // 2.82 MB, reused per gemm
    u16*   act  = (u16*)(ws + 47906816);      // 2.75 MB fp16 (Afrag)
    float* res2 = (float*)(ws + 50724864);    // 2 MB fp32
    u16*   slot = (u16*)(ws + 52822016);      // 1 MB fp16 Afrag (h1/qb/h2)

    // h1 = rmsnorm(x, ln1) -> Afrag ; zs for qkv
    rmsnorm_k<<<128, 256, 0, stream>>>(x, ln1_w, slot);
    pack_zs<<<512, 256, 0, stream>>>(qkv_qz, qkv_sc, zsb, 1536, 12288, 4096, 131072);

    // q = h1 @ Wqkv[:, :4096]   (64m-wave tiles x SK16 -> 4096 waves)
    gemm_awq<2><<<dim3(64, 16), 256, 0, stream>>>(slot, zsb, qkv_qw, pbuf,
                                                  1536, 4096, 4096, 256);
    reduce_to_afrag<<<256, 256, 0, stream>>>(pbuf, slot, 16);
    pack_zs<<<512, 256, 0, stream>>>(o_qz, o_sc, zsb, 512, 4096, 4096, 131072);

    // attn = q @ Wo ; res2 = x + attn
    gemm_awq<2><<<dim3(64, 16), 256, 0, stream>>>(slot, zsb, o_qw, pbuf,
                                                  512, 4096, 4096, 256);
    reduce_add_f32<<<256, 256, 0, stream>>>(pbuf, x, res2, 16);

    // h2 = rmsnorm(res2, ln2) -> Afrag ; zs for gu
    rmsnorm_k<<<128, 256, 0, stream>>>(res2, ln2_w, slot);
    pack_zs<<<2752, 256, 0, stream>>>(gu_qz, gu_sc, zsb, 2752, 22016, 22016, 704512);

    // gate_up = h2 @ Wgu   (128m-wave tiles, SK8 kchunk 512 -> 5504 waves)
    gemm_awq<1><<<dim3(172, 8), 256, 0, stream>>>(slot, zsb, gu_qw, pbuf,
                                                  2752, 22016, 4096, 512);
    silu_mul<<<688, 256, 0, stream>>>(pbuf, act, 8);
    pack_zs<<<1376, 256, 0, stream>>>(dn_qz, dn_sc, zsb, 512, 4096, 4096, 352256);

    // down = act @ Wdn   (64m-wave tiles x SK20, kchunk 576 -> 5120 waves)
    gemm_awq<2><<<dim3(64, 20), 256, 0, stream>>>(act, zsb, dn_qw, pbuf,
                                                  512, 4096, 11008, 576);
    reduce_add_f32<<<256, 256, 0, stream>>>(pbuf, res2, out, 20);
}

// Round 10
// 287.683 us; speedup vs baseline: 1.1078x; 1.1078x over previous
//
#include <hip/hip_runtime.h>

typedef unsigned int   u32;
typedef unsigned short u16;

typedef _Float16 h2  __attribute__((ext_vector_type(2)));
typedef _Float16 h8  __attribute__((ext_vector_type(8)));
typedef float    f32x4 __attribute__((ext_vector_type(4)));

#define M_TOK 128

__device__ __forceinline__ u16 f2h_(float f) {
    _Float16 h = (_Float16)f; return __builtin_bit_cast(u16, h);
}
__device__ __forceinline__ float h2f_(u16 b) {
    _Float16 h = __builtin_bit_cast(_Float16, b); return (float)h;
}
__device__ __forceinline__ void acc8(uint4 v, float* s) {
#pragma unroll
    for (int i = 0; i < 4; ++i) {
        u32 w = ((const u32*)&v)[i];
        s[2 * i]     += h2f_((u16)(w & 0xFFFF));
        s[2 * i + 1] += h2f_((u16)(w >> 16));
    }
}

// AWQ nibble order: n&7 = j sits at bit position SH[j]
__constant__ int SHC[8] = {0, 16, 4, 20, 8, 24, 12, 28};

// ---------------------------------------------------------------------------
// pack_zs: (qz, sc) -> zs[g][n] u32 { lo16: fp16(-(1024+z)), hi16: fp16(sc) }
// ---------------------------------------------------------------------------
__launch_bounds__(256)
__global__ void pack_zs(const int* __restrict__ qz, const float* __restrict__ sc,
                        u32* __restrict__ zs, int qws, int scs, int Ncols, int total) {
    const int idx = blockIdx.x * 256 + threadIdx.x;
    if (idx >= total) return;
    const int g = idx / Ncols, n = idx - g * Ncols;
    const u32 d = (u32)qz[(size_t)g * qws + (n >> 3)];
    const u32 zj = (d >> SHC[n & 7]) & 15u;
    const u32 mz = 0xE400u | zj;                    // fp16 -(1024+z)
    const u16 sh = f2h_(sc[(size_t)g * scs + n]);
    zs[(size_t)g * Ncols + n] = mz | ((u32)sh << 16);
}

// A-fragment-major layout: elem offset for logical (m, k):
//   kb=k/32, q=(k/8)&3, j=k&7, mt=m/16, l16=m&15
//   off = ((kb*8+mt)*64 + q*16 + l16)*8 + j    (fp16 elements)
// => per 32-k block the 8 KB region [kb*8192, kb*8192+8192) bytes is
//    contiguous; a 64-k step = two contiguous 8 KB blobs.

// ---------------------------------------------------------------------------
// RMSNorm: one block per token row, fp32 in -> fp16 out in Afrag layout
// ---------------------------------------------------------------------------
__launch_bounds__(256)
__global__ void rmsnorm_k(const float* __restrict__ in, const float* __restrict__ w,
                          u16* __restrict__ out) {
    const int row = blockIdx.x;
    const float* x = in + (size_t)row * 4096;
    float ss = 0.f;
#pragma unroll
    for (int j = 0; j < 16; ++j) {
        float v = x[threadIdx.x + 256 * j];
        ss += v * v;
    }
#pragma unroll
    for (int off = 32; off > 0; off >>= 1) ss += __shfl_down(ss, off, 64);
    __shared__ float ws4[4];
    if ((threadIdx.x & 63) == 0) ws4[threadIdx.x >> 6] = ss;
    __syncthreads();
    float total = ws4[0] + ws4[1] + ws4[2] + ws4[3];
    float r = rsqrtf(total * (1.f / 4096.f) + 1e-6f);
    const int mt = row >> 4, l16 = row & 15;
#pragma unroll
    for (int c2 = 0; c2 < 2; ++c2) {
        int c = threadIdx.x * 2 + c2;
        int kb = c >> 2, qq = c & 3;
        u16 o8[8];
#pragma unroll
        for (int j = 0; j < 8; ++j) {
            int i = c * 8 + j;
            o8[j] = f2h_(x[i] * r * w[i]);
        }
        *(uint4*)(out + ((size_t)(kb * 8 + mt) * 64 + qq * 16 + l16) * 8) = *(const uint4*)o8;
    }
}

// ---------------------------------------------------------------------------
// AWQ GEMM. Wave = 128m x 32n; block = 4 waves on 4 distinct 32n strips.
// A-staging theory (round 8, still untested -- rounds 8/9 were container
// failures with a raw-s_barrier protocol; this round uses ONLY
// __syncthreads): rounds 0-7 re-read the A step-tile from global per WAVE
// per STEP (~128-160 KB/CU-step through the chip-wide L2) -- the invariant
// ~3000-cycle step wall and pinned ~14% MfmaUtil across all schedule
// variants. Fix: stage the 16 KB A step-tile in LDS once per BLOCK.
// Sync (conservative): A is DOUBLE-buffered -- MFMAs read A[cur] while
// ds_writes fill A[nxt]; one __syncthreads at step end publishes A[nxt].
// B is per-wave private single-buffer: same-wave DS in-order (bv reads
// issued before emit writes) needs no barrier (proven rounds 0/6/7).
// All VMEM (A-stage loads, qw ldraw(i+2)) issues at step TOP and is
// consumed at step BOTTOM, so the __syncthreads vmcnt(0) drain has a full
// compute phase of slack -- no exposed HBM latency.
// LDS 51200 B -> 3 blocks/CU; __launch_bounds__(256,3).
// ---------------------------------------------------------------------------
__launch_bounds__(256, 3)
__global__ void gemm_awq(const u16* __restrict__ A, const u32* __restrict__ zs,
                         const int* __restrict__ qw, u16* __restrict__ part,
                         int qws, int N, int K, int kchunk) {
    __shared__ __align__(16) char lds[51200];   // [0,32K): A dbuf; 32K+w*4608: B

    const int tid = threadIdx.x, w = tid >> 6, lane = tid & 63;
    const int q = lane >> 4, l16 = lane & 15;
    // bijective XCD-chunk swizzle (m204 form)
    const int nwg = gridDim.x, bid = blockIdx.x;
    const int qq8 = nwg >> 3, r8 = nwg & 7, xcd = bid & 7, boff = bid >> 3;
    const int bx = (xcd < r8 ? xcd * (qq8 + 1) : r8 * (qq8 + 1) + (xcd - r8) * qq8) + boff;
    const int n0w = bx * 128 + w * 32;               // this wave's 32n strip
    const int pc0 = n0w >> 3;
    const int kp = lane & 31, h = lane >> 5;
    const int sk = blockIdx.y, kc0 = sk * kchunk, kend = min(kc0 + kchunk, K);

    char* ldsA0 = lds;
    char* ldsA1 = lds + 16384;
    char* myB   = lds + 32768 + w * 4608;
    const char* Ab = (const char*)A;
    const int stoff = w * 4096 + lane * 16;          // staging offset (dst & src)
    const int aoff  = (q * 16 + l16) * 16;           // A-frag lane offset
    const int* qws_base = qw + pc0;
    const u32* zsA = zs + n0w + h * 8;
    const u32* zsB = zs + n0w + 16 + h * 8;

    f32x4 acc[8][2] = {};
    uint4 za0, za1, zb0, zb1;       // current group's packed (mz, sc)

    auto ldraw = [&](int k0) -> uint4 {
        return *(const uint4*)(qws_base + (size_t)(k0 + lane) * qws);
    };
    auto loadzs = [&](int g) {
        za0 = *(const uint4*)(zsA + (size_t)g * N);
        za1 = *(const uint4*)(zsA + (size_t)g * N + 4);
        zb0 = *(const uint4*)(zsB + (size_t)g * N);
        zb1 = *(const uint4*)(zsB + (size_t)g * N + 4);
    };
    auto bperm8 = [&](uint4 rv, int* b) {
        const int i0 = kp * 8, i1 = i0 + 4;
        b[0] = __builtin_amdgcn_ds_bpermute(i0, (int)rv.x);
        b[1] = __builtin_amdgcn_ds_bpermute(i0, (int)rv.y);
        b[2] = __builtin_amdgcn_ds_bpermute(i0, (int)rv.z);
        b[3] = __builtin_amdgcn_ds_bpermute(i0, (int)rv.w);
        b[4] = __builtin_amdgcn_ds_bpermute(i1, (int)rv.x);
        b[5] = __builtin_amdgcn_ds_bpermute(i1, (int)rv.y);
        b[6] = __builtin_amdgcn_ds_bpermute(i1, (int)rv.z);
        b[7] = __builtin_amdgcn_ds_bpermute(i1, (int)rv.w);
    };
    auto emit_all = [&](const int* b, char* buf) {
        u32 qd0 = (u32)(h ? b[1] : b[0]);
        u32 qd1 = (u32)(h ? b[5] : b[4]);
        u32 qd2 = (u32)(h ? b[3] : b[2]);
        u32 qd3 = (u32)(h ? b[7] : b[6]);
        auto emit8 = [&](u32 w0, u32 w1, int nb, uint4 z0, uint4 z1) {
            char* bb = buf + kp * 4 + nb * 144;
            u32 w0s = w0 >> 4, w1s = w1 >> 4;
            auto em = [&](int j, u32 a0, u32 a1, int bsel, u32 zsj) {
                h2 mz = __builtin_bit_cast(h2, __builtin_amdgcn_perm(zsj, zsj, 0x01000100u));
                h2 s2 = __builtin_bit_cast(h2, __builtin_amdgcn_perm(zsj, zsj, 0x03020302u));
                u32 t = __builtin_amdgcn_perm(a1, a0, (u32)(bsel | ((bsel + 4) << 16)));
                u32 u = (t & 0x000F000Fu) | 0x64006400u;
                h2 v = (__builtin_bit_cast(h2, u) + mz) * s2;
                *(u32*)(bb + j * 144) = __builtin_bit_cast(u32, v);
            };
            em(0, w0, w1, 0, z0.x);  em(4, w0, w1, 1, z1.x);
            em(1, w0, w1, 2, z0.y);  em(5, w0, w1, 3, z1.y);
            em(2, w0s, w1s, 0, z0.z); em(6, w0s, w1s, 1, z1.z);
            em(3, w0s, w1s, 2, z0.w); em(7, w0s, w1s, 3, z1.w);
        };
        emit8(qd0, qd1, h * 8, za0, za1);
        emit8(qd2, qd3, 16 + h * 8, zb0, zb1);
    };

    // ---- prologue: stage A(0) into buf0, dequant B(0), raw ring depth 2 ----
    loadzs(kc0 >> 7);
    uint4 rv0 = ldraw(kc0);
    uint4 rv_n = {0, 0, 0, 0};
    if (kc0 + 64 < kend) rv_n = ldraw(kc0 + 64);
    {
        const char* gs = Ab + (size_t)(kc0 >> 5) * 8192 + stoff;
        uint4 s0 = *(const uint4*)(gs);
        uint4 s1 = *(const uint4*)(gs + 1024);
        uint4 s2 = *(const uint4*)(gs + 2048);
        uint4 s3 = *(const uint4*)(gs + 3072);
        *(uint4*)(ldsA0 + stoff)        = s0;
        *(uint4*)(ldsA0 + stoff + 1024) = s1;
        *(uint4*)(ldsA0 + stoff + 2048) = s2;
        *(uint4*)(ldsA0 + stoff + 3072) = s3;
    }
    {
        int bp0[8];
        bperm8(rv0, bp0);
        emit_all(bp0, myB);
    }
    if (((kc0 + 64) & 127) == 0 && kc0 + 64 < kend)
        loadzs((kc0 + 64) >> 7);        // mid-group chunk start
    __syncthreads();

    // ---- main loop: one __syncthreads per step ----
    char* cur = ldsA0; char* nxt = ldsA1;
    int bp[8];
    for (int k0 = kc0; k0 < kend; k0 += 64) {
        const bool kn1 = (k0 + 64) < kend, kn2 = (k0 + 128) < kend;
        // (1) step TOP: all VMEM issues (consumed at step bottom -> full slack)
        uint4 s0 = {0,0,0,0}, s1 = {0,0,0,0}, s2 = {0,0,0,0}, s3 = {0,0,0,0};
        if (kn1) {
            const char* gs = Ab + (size_t)((k0 + 64) >> 5) * 8192 + stoff;
            s0 = *(const uint4*)(gs);
            s1 = *(const uint4*)(gs + 1024);
            s2 = *(const uint4*)(gs + 2048);
            s3 = *(const uint4*)(gs + 3072);
        }
        uint4 rv_f = {0, 0, 0, 0};
        if (kn2) rv_f = ldraw(k0 + 128);
        // (2) c=0: B frags, A frags from cur, bperms (hide under MFMA), MFMA
        {
            uint4 bvc[2];
#pragma unroll
            for (int nt = 0; nt < 2; ++nt)
                bvc[nt] = *(const uint4*)(myB + (nt * 16 + l16) * 144 + q * 16);
            uint4 afc[8];
#pragma unroll
            for (int mt = 0; mt < 8; ++mt)
                afc[mt] = *(const uint4*)(cur + mt * 1024 + aoff);
            if (kn1) bperm8(rv_n, bp);
#pragma unroll
            for (int mt = 0; mt < 8; ++mt)
#pragma unroll
                for (int nt = 0; nt < 2; ++nt)
                    acc[mt][nt] = __builtin_amdgcn_mfma_f32_16x16x32_f16(
                        __builtin_bit_cast(h8, afc[mt]),
                        __builtin_bit_cast(h8, bvc[nt]),
                        acc[mt][nt], 0, 0, 0);
        }
        // (3) c=1
        {
            uint4 bvc[2];
#pragma unroll
            for (int nt = 0; nt < 2; ++nt)
                bvc[nt] = *(const uint4*)(myB + (nt * 16 + l16) * 144 + 64 + q * 16);
            uint4 afc[8];
#pragma unroll
            for (int mt = 0; mt < 8; ++mt)
                afc[mt] = *(const uint4*)(cur + 8192 + mt * 1024 + aoff);
#pragma unroll
            for (int mt = 0; mt < 8; ++mt)
#pragma unroll
                for (int nt = 0; nt < 2; ++nt)
                    acc[mt][nt] = __builtin_amdgcn_mfma_f32_16x16x32_f16(
                        __builtin_bit_cast(h8, afc[mt]),
                        __builtin_bit_cast(h8, bvc[nt]),
                        acc[mt][nt], 0, 0, 0);
        }
        // (4) produce phase: B(i+1) into private myB (same-wave in-order after
        // the bv reads above); A(i+1) into the OTHER A buffer (nxt)
        if (kn1) {
            emit_all(bp, myB);
            *(uint4*)(nxt + stoff)        = s0;
            *(uint4*)(nxt + stoff + 1024) = s1;
            *(uint4*)(nxt + stoff + 2048) = s2;
            *(uint4*)(nxt + stoff + 3072) = s3;
        }
        if (((k0 + 128) & 127) == 0 && (k0 + 128) < kend)
            loadzs((k0 + 128) >> 7);    // zs(group+1), used next step
        // (5) publish A(i+1) to all waves
        __syncthreads();
        rv_n = rv_f;
        char* t = cur; cur = nxt; nxt = t;
    }

    // ---- epilogue: fp16 partial store ----
    u16* pp = part + (size_t)sk * M_TOK * N;
#pragma unroll
    for (int mt = 0; mt < 8; ++mt)
#pragma unroll
        for (int nt = 0; nt < 2; ++nt) {
            const int n = n0w + nt * 16 + l16;
#pragma unroll
            for (int r = 0; r < 4; ++r) {
                const int m = mt * 16 + q * 4 + r;
                pp[(size_t)m * N + n] = f2h_(acc[mt][nt][r]);
            }
        }
}

// ---------------------------------------------------------------------------
__launch_bounds__(256)
__global__ void reduce_to_afrag(const u16* __restrict__ part, u16* __restrict__ out,
                                int SK) {
    const int idx = blockIdx.x * 256 + threadIdx.x;
    const int m = idx >> 9, c = idx & 511;
    float s[8] = {};
    for (int k = 0; k < SK; ++k)
        acc8(*(const uint4*)(part + (size_t)k * 524288 + (size_t)m * 4096 + c * 8), s);
    const int kb = c >> 2, qq = c & 3, mt = m >> 4, l16 = m & 15;
    u16 o8[8];
#pragma unroll
    for (int j = 0; j < 8; ++j) o8[j] = f2h_(s[j]);
    *(uint4*)(out + ((size_t)(kb * 8 + mt) * 64 + qq * 16 + l16) * 8) = *(const uint4*)o8;
}

__launch_bounds__(256)
__global__ void reduce_add_f32(const u16* __restrict__ part, const float* __restrict__ resin,
                               float* __restrict__ out, int SK) {
    const int idx = blockIdx.x * 256 + threadIdx.x;
    const size_t base = (size_t)idx * 8;
    float s[8];
    *(float4*)&s[0] = *(const float4*)(resin + base);
    *(float4*)&s[4] = *(const float4*)(resin + base + 4);
    for (int k = 0; k < SK; ++k)
        acc8(*(const uint4*)(part + (size_t)k * 524288 + base), s);
    *(float4*)(out + base)     = *(const float4*)&s[0];
    *(float4*)(out + base + 4) = *(const float4*)&s[4];
}

__launch_bounds__(256)
__global__ void silu_mul(const u16* __restrict__ part, u16* __restrict__ act, int SK) {
    const int idx = blockIdx.x * 256 + threadIdx.x;
    const int m = idx / 1376, c = idx - m * 1376;
    const int nb = c * 8;
    float g[8] = {}, u[8] = {};
    for (int k = 0; k < SK; ++k) {
        const size_t base = (size_t)k * 2818048 + (size_t)m * 22016 + nb;
        acc8(*(const uint4*)(part + base), g);
        acc8(*(const uint4*)(part + base + 11008), u);
    }
    const int kb = nb >> 5, qq = (nb >> 3) & 3, mt = m >> 4, l16 = m & 15;
    u16 o8[8];
#pragma unroll
    for (int j = 0; j < 8; ++j) {
        float a = g[j] / (1.f + __expf(-g[j])) * u[j];
        o8[j] = f2h_(a);
    }
    *(uint4*)(act + ((size_t)(kb * 8 + mt) * 64 + qq * 16 + l16) * 8) = *(const uint4*)o8;
}

// ---------------------------------------------------------------------------
extern "C" void kernel_launch(void* const* d_in, const int* in_sizes, int n_in,
                              void* d_out, int out_size, void* d_ws, size_t ws_size,
                              hipStream_t stream) {
    const float* x      = (const float*)d_in[0];
    const float* ln1_w  = (const float*)d_in[1];
    const float* ln2_w  = (const float*)d_in[2];
    const int*   qkv_qw = (const int*)d_in[3];
    const int*   qkv_qz = (const int*)d_in[4];
    const float* qkv_sc = (const float*)d_in[5];
    const int*   o_qw   = (const int*)d_in[6];
    const int*   o_qz   = (const int*)d_in[7];
    const float* o_sc   = (const float*)d_in[8];
    const int*   gu_qw  = (const int*)d_in[9];
    const int*   gu_qz  = (const int*)d_in[10];
    const float* gu_sc  = (const float*)d_in[11];
    const int*   dn_qw  = (const int*)d_in[12];
    const int*   dn_qz  = (const int*)d_in[13];
    const float* dn_sc  = (const float*)d_in[14];
    float* out = (float*)d_out;

    // ws layout (~53.9 MB; >= 70.8 MB available, proven in round 3)
    char* ws = (char*)d_ws;
    u16*   pbuf = (u16*)(ws);                 // partials: max 28.2 MB (gu SK5)
    u32*   zsb  = (u32*)(ws + 45088768);      // 2.82 MB, reused per gemm
    u16*   act  = (u16*)(ws + 47906816);      // 2.75 MB fp16 (Afrag)
    float* res2 = (float*)(ws + 50724864);    // 2 MB fp32
    u16*   slot = (u16*)(ws + 52822016);      // 1 MB fp16 Afrag (h1/qb/h2)

    // h1 = rmsnorm(x, ln1) -> Afrag ; zs for qkv
    rmsnorm_k<<<128, 256, 0, stream>>>(x, ln1_w, slot);
    pack_zs<<<512, 256, 0, stream>>>(qkv_qz, qkv_sc, zsb, 1536, 12288, 4096, 131072);

    // q = h1 @ Wqkv[:, :4096]   (32 tiles x SK22, kchunk 192 -> 704 blocks)
    gemm_awq<<<dim3(32, 22), 256, 0, stream>>>(slot, zsb, qkv_qw, pbuf,
                                               1536, 4096, 4096, 192);
    reduce_to_afrag<<<256, 256, 0, stream>>>(pbuf, slot, 22);
    pack_zs<<<512, 256, 0, stream>>>(o_qz, o_sc, zsb, 512, 4096, 4096, 131072);

    // attn = q @ Wo ; res2 = x + attn
    gemm_awq<<<dim3(32, 22), 256, 0, stream>>>(slot, zsb, o_qw, pbuf,
                                               512, 4096, 4096, 192);
    reduce_add_f32<<<256, 256, 0, stream>>>(pbuf, x, res2, 22);

    // h2 = rmsnorm(res2, ln2) -> Afrag ; zs for gu
    rmsnorm_k<<<128, 256, 0, stream>>>(res2, ln2_w, slot);
    pack_zs<<<2752, 256, 0, stream>>>(gu_qz, gu_sc, zsb, 2752, 22016, 22016, 704512);

    // gate_up = h2 @ Wgu   (172 tiles x SK5, kchunk 832 -> 860 blocks)
    gemm_awq<<<dim3(172, 5), 256, 0, stream>>>(slot, zsb, gu_qw, pbuf,
                                               2752, 22016, 4096, 832);
    silu_mul<<<688, 256, 0, stream>>>(pbuf, act, 5);
    pack_zs<<<1376, 256, 0, stream>>>(dn_qz, dn_sc, zsb, 512, 4096, 4096, 352256);

    // down = act @ Wdn   (32 tiles x SK25, kchunk 448 -> 800 blocks)
    gemm_awq<<<dim3(32, 25), 256, 0, stream>>>(act, zsb, dn_qw, pbuf,
                                               512, 4096, 11008, 448);
    reduce_add_f32<<<256, 256, 0, stream>>>(pbuf, res2, out, 25);
}